// Round 6
// baseline (238.999 us; speedup 1.0000x reference)
//
#include <hip/hip_runtime.h>
#include <stdint.h>

#define T_DIM 8192
#define B_DIM 4096
#define NSEG 32                 // 32 segments x 256 rows (8 word-rows) each
#define CTILE 256               // columns per block
#define NEG_SLOPE 0.01f

// Split streaming design. Thread = 16 rows x 4 cols (half a 32-bit word per
// column). 1024-thr blocks, grid (16,32) = 512 blocks = 8192 waves = 32
// waves/CU at 2 blocks/CU. NO nontemporal hints: the harness's d_in restore
// copy / d_out poison fill leave both arrays L2/L3-resident right before we
// run, so we WANT cache hits on input reads and cache absorption of output
// stores (drain overlaps the next harness fill).

// ---------------------------------------------------------------------------
// KA: stream input, pack bits, publish per-segment column totals.
// Block = one segment x 256 cols.
// ---------------------------------------------------------------------------
__global__ __launch_bounds__(1024, 8) void ka_pack(const int* __restrict__ in,
                                                   uint32_t* __restrict__ bits,
                                                   int* __restrict__ segTotal) {
    const int c4   = threadIdx.x & 63;         // column-quad lane
    const int rr   = threadIdx.x >> 6;         // 0..15: (word-row-local, half)
    const int wl   = rr >> 1;                  // word-row within segment, 0..7
    const int half = rr & 1;                   // 0 = bits 0..15, 1 = bits 16..31
    const int col0 = blockIdx.x * CTILE + c4 * 4;
    const int wordrow = blockIdx.y * 8 + wl;   // global word row, 0..255
    const int row0 = wordrow * 32 + half * 16;

    const int4* __restrict__ inv = (const int4*)in;
    uint32_t b0 = 0, b1 = 0, b2 = 0, b3 = 0;
#pragma unroll
    for (int r = 0; r < 16; ++r) {
        int4 v = inv[((size_t)(row0 + r) * B_DIM + col0) >> 2];
        b0 |= ((uint32_t)v.x & 1u) << r;
        b1 |= ((uint32_t)v.y & 1u) << r;
        b2 |= ((uint32_t)v.z & 1u) << r;
        b3 |= ((uint32_t)v.w & 1u) << r;
    }

    __shared__ uint4 halves[16][64];
    __shared__ int4  cnts[8][64];
    halves[rr][c4] = make_uint4(b0, b1, b2, b3);
    __syncthreads();

    if (half == 0) {
        uint4 lo = halves[rr][c4];
        uint4 hi = halves[rr + 1][c4];
        uint4 w = make_uint4(lo.x | (hi.x << 16), lo.y | (hi.y << 16),
                             lo.z | (hi.z << 16), lo.w | (hi.w << 16));
        ((uint4*)bits)[((size_t)wordrow * B_DIM + col0) >> 2] = w;
        cnts[wl][c4] = make_int4(__popc(w.x), __popc(w.y), __popc(w.z), __popc(w.w));
    }
    __syncthreads();

    if (rr == 0) {  // wave 0: column totals for this segment
        int4 s = make_int4(0, 0, 0, 0);
#pragma unroll
        for (int i = 0; i < 8; ++i) {
            int4 v = cnts[i][c4];
            s.x += v.x; s.y += v.y; s.z += v.z; s.w += v.w;
        }
        ((int4*)segTotal)[((size_t)blockIdx.y * B_DIM + col0) >> 2] = s;
    }
}

// ---------------------------------------------------------------------------
// KB: reload packed bits (4 MB, L2/L3-hot) + segment totals, reconstruct the
// exact prefix count, emit leaky_relu via float4 stores.
// ---------------------------------------------------------------------------
__global__ __launch_bounds__(1024, 8) void kb_emit(const uint32_t* __restrict__ bits,
                                                   const int* __restrict__ segTotal,
                                                   const float* __restrict__ delta,
                                                   float* __restrict__ out) {
    const int c4   = threadIdx.x & 63;
    const int rr   = threadIdx.x >> 6;
    const int wl   = rr >> 1;
    const int half = rr & 1;
    const int col0 = blockIdx.x * CTILE + c4 * 4;
    const int seg  = blockIdx.y;
    const int wordrow = seg * 8 + wl;
    const int row0 = wordrow * 32 + half * 16;

    uint4 w = ((const uint4*)bits)[((size_t)wordrow * B_DIM + col0) >> 2];

    __shared__ int4 cnts[8][64];
    if (half == 0)
        cnts[wl][c4] = make_int4(__popc(w.x), __popc(w.y), __popc(w.z), __popc(w.w));

    // base from preceding segments (same addrs across waves -> L1 broadcast)
    int c0 = 0, c1 = 0, c2 = 0, c3 = 0;
    for (int s = 0; s < seg; ++s) {
        int4 v = ((const int4*)segTotal)[((size_t)s * B_DIM + col0) >> 2];
        c0 += v.x; c1 += v.y; c2 += v.z; c3 += v.w;
    }
    __syncthreads();

    // + preceding word-rows within segment (wl is wave-uniform)
    for (int i = 0; i < wl; ++i) {
        int4 v = cnts[i][c4];
        c0 += v.x; c1 += v.y; c2 += v.z; c3 += v.w;
    }
    // + lower half of own word if this thread handles the upper half
    if (half) {
        c0 += __popc(w.x & 0xFFFFu);
        c1 += __popc(w.y & 0xFFFFu);
        c2 += __popc(w.z & 0xFFFFu);
        c3 += __popc(w.w & 0xFFFFu);
    }

    const float d0 = delta[0];
    const float dd = delta[1] - d0;
    const int sh = half * 16;

    float4* __restrict__ outv = (float4*)out;
#pragma unroll
    for (int r = 0; r < 16; ++r) {
        const int t = row0 + r;
        const float tp = (float)(t + 1) * d0;
        c0 += (int)((w.x >> (sh + r)) & 1u);
        c1 += (int)((w.y >> (sh + r)) & 1u);
        c2 += (int)((w.z >> (sh + r)) & 1u);
        c3 += (int)((w.w >> (sh + r)) & 1u);
        float4 o;
        o.x = fmaf((float)c0, dd, tp);
        o.y = fmaf((float)c1, dd, tp);
        o.z = fmaf((float)c2, dd, tp);
        o.w = fmaf((float)c3, dd, tp);
        o.x = (o.x >= 0.0f) ? o.x : NEG_SLOPE * o.x;
        o.y = (o.y >= 0.0f) ? o.y : NEG_SLOPE * o.y;
        o.z = (o.z >= 0.0f) ? o.z : NEG_SLOPE * o.z;
        o.w = (o.w >= 0.0f) ? o.w : NEG_SLOPE * o.w;
        outv[((size_t)t * B_DIM + col0) >> 2] = o;
    }
}

extern "C" void kernel_launch(void* const* d_in, const int* in_sizes, int n_in,
                              void* d_out, int out_size, void* d_ws, size_t ws_size,
                              hipStream_t stream) {
    const int*   in    = (const int*)d_in[0];
    const float* delta = (const float*)d_in[1];
    float*       out   = (float*)d_out;

    uint32_t* bits     = (uint32_t*)d_ws;                                    // 4 MiB
    int*      segTotal = (int*)((char*)d_ws + (size_t)(T_DIM / 32) * B_DIM * 4);

    dim3 grid(B_DIM / CTILE, NSEG);   // (16, 32) = 512 blocks
    dim3 block(1024);

    hipLaunchKernelGGL(ka_pack, grid, block, 0, stream, in, bits, segTotal);
    hipLaunchKernelGGL(kb_emit, grid, block, 0, stream, bits, segTotal, delta, out);
}

// Round 7
// 226.063 us; speedup vs baseline: 1.0572x; 1.0572x over previous
//
#include <hip/hip_runtime.h>
#include <stdint.h>

#define T_DIM 8192
#define B_DIM 4096
#define NSEG 32                 // 32 segments x 256 rows (8 word-rows) each
#define CTILE 256               // columns per block
#define NEG_SLOPE 0.01f

// Native clang vector types: __builtin_nontemporal_* requires these.
typedef int      ivec4 __attribute__((ext_vector_type(4)));
typedef float    fvec4 __attribute__((ext_vector_type(4)));
typedef unsigned uvec4 __attribute__((ext_vector_type(4)));

// Split streaming design (round-5 winner + nt on KB's bits load).
// A/B evidence: nt hints on the single-use streams = -13 us (r5 226 vs r6 239).
// The harness's 512 MiB ws poison flushes L3 between the d_in restore and our
// kernels, so input reads are cold HBM; nt avoids polluting L2 on reads and
// avoids write-allocate churn on the 128 MiB output stream.

// ---------------------------------------------------------------------------
// KA: stream input (nt loads), pack bits, publish per-segment column totals.
// Thread = 16 rows x 4 cols; block = one segment x 256 cols.
// ---------------------------------------------------------------------------
__global__ __launch_bounds__(1024, 8) void ka_pack(const int* __restrict__ in,
                                                   uint32_t* __restrict__ bits,
                                                   int* __restrict__ segTotal) {
    const int c4   = threadIdx.x & 63;         // column-quad lane
    const int rr   = threadIdx.x >> 6;         // 0..15: (word-row-local, half)
    const int wl   = rr >> 1;                  // word-row within segment, 0..7
    const int half = rr & 1;                   // 0 = bits 0..15, 1 = bits 16..31
    const int col0 = blockIdx.x * CTILE + c4 * 4;
    const int wordrow = blockIdx.y * 8 + wl;   // global word row, 0..255
    const int row0 = wordrow * 32 + half * 16;

    const ivec4* __restrict__ inv = (const ivec4*)in;
    uint32_t b0 = 0, b1 = 0, b2 = 0, b3 = 0;
#pragma unroll
    for (int r = 0; r < 16; ++r) {
        ivec4 v = __builtin_nontemporal_load(&inv[((size_t)(row0 + r) * B_DIM + col0) >> 2]);
        b0 |= ((uint32_t)v.x & 1u) << r;
        b1 |= ((uint32_t)v.y & 1u) << r;
        b2 |= ((uint32_t)v.z & 1u) << r;
        b3 |= ((uint32_t)v.w & 1u) << r;
    }

    __shared__ uint4 halves[16][64];
    __shared__ int4  cnts[8][64];
    halves[rr][c4] = make_uint4(b0, b1, b2, b3);
    __syncthreads();

    if (half == 0) {
        uint4 lo = halves[rr][c4];
        uint4 hi = halves[rr + 1][c4];
        uint4 w = make_uint4(lo.x | (hi.x << 16), lo.y | (hi.y << 16),
                             lo.z | (hi.z << 16), lo.w | (hi.w << 16));
        ((uint4*)bits)[((size_t)wordrow * B_DIM + col0) >> 2] = w;
        cnts[wl][c4] = make_int4(__popc(w.x), __popc(w.y), __popc(w.z), __popc(w.w));
    }
    __syncthreads();

    if (rr == 0) {  // wave 0: column totals for this segment
        int4 s = make_int4(0, 0, 0, 0);
#pragma unroll
        for (int i = 0; i < 8; ++i) {
            int4 v = cnts[i][c4];
            s.x += v.x; s.y += v.y; s.z += v.z; s.w += v.w;
        }
        ((int4*)segTotal)[((size_t)blockIdx.y * B_DIM + col0) >> 2] = s;
    }
}

// ---------------------------------------------------------------------------
// KB: reload packed bits (read-once -> nt) + segment totals (read 16x, plain),
// reconstruct exact prefix count, emit leaky_relu via nt float4 stores.
// ---------------------------------------------------------------------------
__global__ __launch_bounds__(1024, 8) void kb_emit(const uint32_t* __restrict__ bits,
                                                   const int* __restrict__ segTotal,
                                                   const float* __restrict__ delta,
                                                   float* __restrict__ out) {
    const int c4   = threadIdx.x & 63;
    const int rr   = threadIdx.x >> 6;
    const int wl   = rr >> 1;
    const int half = rr & 1;
    const int col0 = blockIdx.x * CTILE + c4 * 4;
    const int seg  = blockIdx.y;
    const int wordrow = seg * 8 + wl;
    const int row0 = wordrow * 32 + half * 16;

    uvec4 w = __builtin_nontemporal_load(
        &((const uvec4*)bits)[((size_t)wordrow * B_DIM + col0) >> 2]);

    __shared__ int4 cnts[8][64];
    if (half == 0)
        cnts[wl][c4] = make_int4(__popc(w.x), __popc(w.y), __popc(w.z), __popc(w.w));

    // base from preceding segments (same addrs across waves -> L1 broadcast)
    int c0 = 0, c1 = 0, c2 = 0, c3 = 0;
    for (int s = 0; s < seg; ++s) {
        int4 v = ((const int4*)segTotal)[((size_t)s * B_DIM + col0) >> 2];
        c0 += v.x; c1 += v.y; c2 += v.z; c3 += v.w;
    }
    __syncthreads();

    // + preceding word-rows within segment (wl is wave-uniform)
    for (int i = 0; i < wl; ++i) {
        int4 v = cnts[i][c4];
        c0 += v.x; c1 += v.y; c2 += v.z; c3 += v.w;
    }
    // + lower half of own word if this thread handles the upper half
    if (half) {
        c0 += __popc(w.x & 0xFFFFu);
        c1 += __popc(w.y & 0xFFFFu);
        c2 += __popc(w.z & 0xFFFFu);
        c3 += __popc(w.w & 0xFFFFu);
    }

    const float d0 = delta[0];
    const float dd = delta[1] - d0;
    const int sh = half * 16;

    fvec4* __restrict__ outv = (fvec4*)out;
#pragma unroll
    for (int r = 0; r < 16; ++r) {
        const int t = row0 + r;
        const float tp = (float)(t + 1) * d0;
        c0 += (int)((w.x >> (sh + r)) & 1u);
        c1 += (int)((w.y >> (sh + r)) & 1u);
        c2 += (int)((w.z >> (sh + r)) & 1u);
        c3 += (int)((w.w >> (sh + r)) & 1u);
        fvec4 o;
        float ox = fmaf((float)c0, dd, tp);
        float oy = fmaf((float)c1, dd, tp);
        float oz = fmaf((float)c2, dd, tp);
        float ow = fmaf((float)c3, dd, tp);
        o.x = (ox >= 0.0f) ? ox : NEG_SLOPE * ox;
        o.y = (oy >= 0.0f) ? oy : NEG_SLOPE * oy;
        o.z = (oz >= 0.0f) ? oz : NEG_SLOPE * oz;
        o.w = (ow >= 0.0f) ? ow : NEG_SLOPE * ow;
        __builtin_nontemporal_store(o, &outv[((size_t)t * B_DIM + col0) >> 2]);
    }
}

extern "C" void kernel_launch(void* const* d_in, const int* in_sizes, int n_in,
                              void* d_out, int out_size, void* d_ws, size_t ws_size,
                              hipStream_t stream) {
    const int*   in    = (const int*)d_in[0];
    const float* delta = (const float*)d_in[1];
    float*       out   = (float*)d_out;

    uint32_t* bits     = (uint32_t*)d_ws;                                    // 4 MiB
    int*      segTotal = (int*)((char*)d_ws + (size_t)(T_DIM / 32) * B_DIM * 4);

    dim3 grid(B_DIM / CTILE, NSEG);   // (16, 32) = 512 blocks
    dim3 block(1024);

    hipLaunchKernelGGL(ka_pack, grid, block, 0, stream, in, bits, segTotal);
    hipLaunchKernelGGL(kb_emit, grid, block, 0, stream, bits, segTotal, delta, out);
}

// Round 8
// 225.300 us; speedup vs baseline: 1.0608x; 1.0034x over previous
//
#include <hip/hip_runtime.h>
#include <stdint.h>

#define T_DIM 8192
#define B_DIM 4096
#define NSEG 16                 // 16 segments x 512 rows (16 word-rows) each
#define CTILE 256               // columns per block
#define NEG_SLOPE 0.01f

// Native clang vector types: __builtin_nontemporal_* requires these.
typedef int      ivec4 __attribute__((ext_vector_type(4)));
typedef float    fvec4 __attribute__((ext_vector_type(4)));
typedef unsigned uvec4 __attribute__((ext_vector_type(4)));

// Round-1 geometry (thread = full 32-row word x 4 cols; no LDS halves merge,
// one barrier in KA) + round-5 wins (nt hints on single-use streams,
// launch_bounds(1024,8) -> 2 blocks/CU = 32 waves/CU).
// A/B evidence: nt = -13 us (r5 226 vs r6 239); bits-nt neutral (r7).

// ---------------------------------------------------------------------------
// KA: stream input (nt loads), pack 32 rows x 4 cols into register bit-words,
// write bits, publish per-segment column totals. Block = 256 cols x 512 rows.
// ---------------------------------------------------------------------------
__global__ __launch_bounds__(1024, 8) void ka_pack(const int* __restrict__ in,
                                                   uint32_t* __restrict__ bits,
                                                   int* __restrict__ segTotal) {
    const int c4 = threadIdx.x & 63;           // column-quad lane
    const int rc = threadIdx.x >> 6;           // word-row within segment, 0..15
    const int col0 = blockIdx.x * CTILE + c4 * 4;
    const int wordrow = blockIdx.y * 16 + rc;  // global word row 0..255
    const int row0 = wordrow * 32;

    const ivec4* __restrict__ inv = (const ivec4*)in;
    uint32_t b0 = 0, b1 = 0, b2 = 0, b3 = 0;
#pragma unroll
    for (int r = 0; r < 32; ++r) {
        ivec4 v = __builtin_nontemporal_load(&inv[((size_t)(row0 + r) * B_DIM + col0) >> 2]);
        b0 |= ((uint32_t)v.x & 1u) << r;
        b1 |= ((uint32_t)v.y & 1u) << r;
        b2 |= ((uint32_t)v.z & 1u) << r;
        b3 |= ((uint32_t)v.w & 1u) << r;
    }

    ((uint4*)bits)[((size_t)wordrow * B_DIM + col0) >> 2] = make_uint4(b0, b1, b2, b3);

    __shared__ int4 cnts[16][64];
    cnts[rc][c4] = make_int4(__popc(b0), __popc(b1), __popc(b2), __popc(b3));
    __syncthreads();

    if (rc == 0) {  // wave 0: column totals for this segment
        int4 s = make_int4(0, 0, 0, 0);
#pragma unroll
        for (int i = 0; i < 16; ++i) {
            int4 v = cnts[i][c4];
            s.x += v.x; s.y += v.y; s.z += v.z; s.w += v.w;
        }
        ((int4*)segTotal)[((size_t)blockIdx.y * B_DIM + col0) >> 2] = s;
    }
}

// ---------------------------------------------------------------------------
// KB: reload packed bits (read-once -> nt) + segment totals (read 16x, plain),
// reconstruct exact prefix count, emit leaky_relu via nt float4 stores.
// ---------------------------------------------------------------------------
__global__ __launch_bounds__(1024, 8) void kb_emit(const uint32_t* __restrict__ bits,
                                                   const int* __restrict__ segTotal,
                                                   const float* __restrict__ delta,
                                                   float* __restrict__ out) {
    const int c4 = threadIdx.x & 63;
    const int rc = threadIdx.x >> 6;
    const int col0 = blockIdx.x * CTILE + c4 * 4;
    const int seg = blockIdx.y;
    const int wordrow = seg * 16 + rc;
    const int row0 = wordrow * 32;

    uvec4 w = __builtin_nontemporal_load(
        &((const uvec4*)bits)[((size_t)wordrow * B_DIM + col0) >> 2]);

    __shared__ int4 cnts[16][64];
    cnts[rc][c4] = make_int4(__popc(w.x), __popc(w.y), __popc(w.z), __popc(w.w));

    // base from preceding segments (same addrs across waves -> L1 broadcast)
    int c0 = 0, c1 = 0, c2 = 0, c3 = 0;
    for (int s = 0; s < seg; ++s) {
        int4 v = ((const int4*)segTotal)[((size_t)s * B_DIM + col0) >> 2];
        c0 += v.x; c1 += v.y; c2 += v.z; c3 += v.w;
    }
    __syncthreads();

    // + preceding word-rows within segment (rc is wave-uniform)
    for (int i = 0; i < rc; ++i) {
        int4 v = cnts[i][c4];
        c0 += v.x; c1 += v.y; c2 += v.z; c3 += v.w;
    }

    const float d0 = delta[0];
    const float dd = delta[1] - d0;

    fvec4* __restrict__ outv = (fvec4*)out;
#pragma unroll
    for (int r = 0; r < 32; ++r) {
        const int t = row0 + r;
        const float tp = (float)(t + 1) * d0;
        c0 += (int)((w.x >> r) & 1u);
        c1 += (int)((w.y >> r) & 1u);
        c2 += (int)((w.z >> r) & 1u);
        c3 += (int)((w.w >> r) & 1u);
        fvec4 o;
        float ox = fmaf((float)c0, dd, tp);
        float oy = fmaf((float)c1, dd, tp);
        float oz = fmaf((float)c2, dd, tp);
        float ow = fmaf((float)c3, dd, tp);
        o.x = (ox >= 0.0f) ? ox : NEG_SLOPE * ox;
        o.y = (oy >= 0.0f) ? oy : NEG_SLOPE * oy;
        o.z = (oz >= 0.0f) ? oz : NEG_SLOPE * oz;
        o.w = (ow >= 0.0f) ? ow : NEG_SLOPE * ow;
        __builtin_nontemporal_store(o, &outv[((size_t)t * B_DIM + col0) >> 2]);
    }
}

extern "C" void kernel_launch(void* const* d_in, const int* in_sizes, int n_in,
                              void* d_out, int out_size, void* d_ws, size_t ws_size,
                              hipStream_t stream) {
    const int*   in    = (const int*)d_in[0];
    const float* delta = (const float*)d_in[1];
    float*       out   = (float*)d_out;

    uint32_t* bits     = (uint32_t*)d_ws;                                    // 4 MiB
    int*      segTotal = (int*)((char*)d_ws + (size_t)(T_DIM / 32) * B_DIM * 4);

    dim3 grid(B_DIM / CTILE, NSEG);   // (16, 16) = 256 blocks
    dim3 block(1024);

    hipLaunchKernelGGL(ka_pack, grid, block, 0, stream, in, bits, segTotal);
    hipLaunchKernelGGL(kb_emit, grid, block, 0, stream, bits, segTotal, delta, out);
}

// Round 9
// 224.340 us; speedup vs baseline: 1.0653x; 1.0043x over previous
//
#include <hip/hip_runtime.h>
#include <stdint.h>

#define T_DIM 8192
#define B_DIM 4096
#define NSEG 64                 // 64 segments x 128 rows (4 word-rows) each
#define CTILE 256               // columns per block
#define NEG_SLOPE 0.01f

// Native clang vector types: __builtin_nontemporal_* requires these.
typedef int      ivec4 __attribute__((ext_vector_type(4)));
typedef float    fvec4 __attribute__((ext_vector_type(4)));
typedef unsigned uvec4 __attribute__((ext_vector_type(4)));

// Round-8 algorithm at fill-engine dispatch granularity: 256-thr blocks
// (4 waves), 1024 blocks (4/CU). Thread = 32 rows x 4 cols. nt hints on the
// single-use streams (A/B: -13 us, r5 vs r6).

// ---------------------------------------------------------------------------
// KA: stream input (nt loads), pack 32 rows x 4 cols into register bit-words,
// write bits, publish per-segment column totals. Block = 256 cols x 128 rows.
// ---------------------------------------------------------------------------
__global__ __launch_bounds__(256, 4) void ka_pack(const int* __restrict__ in,
                                                  uint32_t* __restrict__ bits,
                                                  int* __restrict__ segTotal) {
    const int c4 = threadIdx.x & 63;           // column-quad lane
    const int rc = threadIdx.x >> 6;           // word-row within segment, 0..3
    const int col0 = blockIdx.x * CTILE + c4 * 4;
    const int wordrow = blockIdx.y * 4 + rc;   // global word row 0..255
    const int row0 = wordrow * 32;

    const ivec4* __restrict__ inv = (const ivec4*)in;
    uint32_t b0 = 0, b1 = 0, b2 = 0, b3 = 0;
#pragma unroll
    for (int r = 0; r < 32; ++r) {
        ivec4 v = __builtin_nontemporal_load(&inv[((size_t)(row0 + r) * B_DIM + col0) >> 2]);
        b0 |= ((uint32_t)v.x & 1u) << r;
        b1 |= ((uint32_t)v.y & 1u) << r;
        b2 |= ((uint32_t)v.z & 1u) << r;
        b3 |= ((uint32_t)v.w & 1u) << r;
    }

    ((uint4*)bits)[((size_t)wordrow * B_DIM + col0) >> 2] = make_uint4(b0, b1, b2, b3);

    __shared__ int4 cnts[4][64];
    cnts[rc][c4] = make_int4(__popc(b0), __popc(b1), __popc(b2), __popc(b3));
    __syncthreads();

    if (rc == 0) {  // wave 0: column totals for this segment (4 word-rows)
        int4 s = cnts[0][c4];
#pragma unroll
        for (int i = 1; i < 4; ++i) {
            int4 v = cnts[i][c4];
            s.x += v.x; s.y += v.y; s.z += v.z; s.w += v.w;
        }
        ((int4*)segTotal)[((size_t)blockIdx.y * B_DIM + col0) >> 2] = s;
    }
}

// ---------------------------------------------------------------------------
// KB: reload packed bits (nt) + segment totals (<=63 independent L2-hot int4
// loads), reconstruct exact prefix count, emit leaky_relu via nt stores.
// ---------------------------------------------------------------------------
__global__ __launch_bounds__(256, 4) void kb_emit(const uint32_t* __restrict__ bits,
                                                  const int* __restrict__ segTotal,
                                                  const float* __restrict__ delta,
                                                  float* __restrict__ out) {
    const int c4 = threadIdx.x & 63;
    const int rc = threadIdx.x >> 6;
    const int col0 = blockIdx.x * CTILE + c4 * 4;
    const int seg = blockIdx.y;
    const int wordrow = seg * 4 + rc;
    const int row0 = wordrow * 32;

    uvec4 w = __builtin_nontemporal_load(
        &((const uvec4*)bits)[((size_t)wordrow * B_DIM + col0) >> 2]);

    __shared__ int4 cnts[4][64];
    cnts[rc][c4] = make_int4(__popc(w.x), __popc(w.y), __popc(w.z), __popc(w.w));

    // base from preceding segments (independent loads, L2-hot 1 MB array,
    // same addrs across waves/blocks of a column tile -> broadcast-friendly)
    int c0 = 0, c1 = 0, c2 = 0, c3 = 0;
    for (int s = 0; s < seg; ++s) {
        int4 v = ((const int4*)segTotal)[((size_t)s * B_DIM + col0) >> 2];
        c0 += v.x; c1 += v.y; c2 += v.z; c3 += v.w;
    }
    __syncthreads();

    // + preceding word-rows within segment (rc is wave-uniform)
    for (int i = 0; i < rc; ++i) {
        int4 v = cnts[i][c4];
        c0 += v.x; c1 += v.y; c2 += v.z; c3 += v.w;
    }

    const float d0 = delta[0];
    const float dd = delta[1] - d0;

    fvec4* __restrict__ outv = (fvec4*)out;
#pragma unroll
    for (int r = 0; r < 32; ++r) {
        const int t = row0 + r;
        const float tp = (float)(t + 1) * d0;
        c0 += (int)((w.x >> r) & 1u);
        c1 += (int)((w.y >> r) & 1u);
        c2 += (int)((w.z >> r) & 1u);
        c3 += (int)((w.w >> r) & 1u);
        fvec4 o;
        float ox = fmaf((float)c0, dd, tp);
        float oy = fmaf((float)c1, dd, tp);
        float oz = fmaf((float)c2, dd, tp);
        float ow = fmaf((float)c3, dd, tp);
        o.x = (ox >= 0.0f) ? ox : NEG_SLOPE * ox;
        o.y = (oy >= 0.0f) ? oy : NEG_SLOPE * oy;
        o.z = (oz >= 0.0f) ? oz : NEG_SLOPE * oz;
        o.w = (ow >= 0.0f) ? ow : NEG_SLOPE * ow;
        __builtin_nontemporal_store(o, &outv[((size_t)t * B_DIM + col0) >> 2]);
    }
}

extern "C" void kernel_launch(void* const* d_in, const int* in_sizes, int n_in,
                              void* d_out, int out_size, void* d_ws, size_t ws_size,
                              hipStream_t stream) {
    const int*   in    = (const int*)d_in[0];
    const float* delta = (const float*)d_in[1];
    float*       out   = (float*)d_out;

    uint32_t* bits     = (uint32_t*)d_ws;                                    // 4 MiB
    int*      segTotal = (int*)((char*)d_ws + (size_t)(T_DIM / 32) * B_DIM * 4);

    dim3 grid(B_DIM / CTILE, NSEG);   // (16, 64) = 1024 blocks
    dim3 block(256);

    hipLaunchKernelGGL(ka_pack, grid, block, 0, stream, in, bits, segTotal);
    hipLaunchKernelGGL(kb_emit, grid, block, 0, stream, bits, segTotal, delta, out);
}